// Round 12
// baseline (46045.526 us; speedup 1.0000x reference)
//
#include <hip/hip_runtime.h>
#include <stdint.h>

#define T_STEPS 1024
#define BATCH   64
#define DIN     256
#define HDIM    512
#define G4      2048
#define NGRP    8        // groups = XCDs
#define GWG     32       // WGs per group
#define GB      8        // batches per group
#define NBUF    16       // h ring depth (guarantees L1 eviction between slot reuses)
#define BLOCK   512

// ---- workspace layout (bytes) ----
#define OFF_XCNT  0                            // 8 ints: per-XCD rank counters
#define OFF_BIAS  8192                         // 2048 f32 (b_ih + b_hh)
#define OFF_WHH   16384                        // 2048*512 bf16 (2 MB)
#define OFF_WIH   (OFF_WHH + G4*HDIM*2)        // 2048*256 bf16 (1 MB)
#define OFF_H     (OFF_WIH + G4*DIN*2)         // [NGRP][NBUF][8][512] u32 (tagged) = 2 MB
#define RING_BYTES (NGRP * NBUF * GB * HDIM * 4)

typedef __attribute__((ext_vector_type(8))) short bf16x8;
typedef __attribute__((ext_vector_type(4))) float f32x4;
typedef __attribute__((ext_vector_type(4))) unsigned u32x4;

__device__ __forceinline__ unsigned short f2bf(float f) {
  union { float f; unsigned u; } v; v.f = f;
  unsigned r = v.u + 0x7FFF + ((v.u >> 16) & 1);
  return (unsigned short)(r >> 16);
}
__device__ __forceinline__ float sigm(float x)   { return 1.0f / (1.0f + __expf(-x)); }
__device__ __forceinline__ float tanh_f(float x) { return 2.0f / (1.0f + __expf(-2.0f * x)) - 1.0f; }

// zero rank counters + ENTIRE tag ring (replay safety: stale tags must not alias)
__global__ void k_init(unsigned char* ws) {
  int tid = blockIdx.x * blockDim.x + threadIdx.x;
  unsigned* w32 = (unsigned*)ws;
  if (tid < 256) w32[tid] = 0;
  u32x4* ring = (u32x4*)(ws + OFF_H);
  int n = RING_BYTES / 16;
  for (int i = tid; i < n; i += gridDim.x * blockDim.x)
    ring[i] = (u32x4){0u, 0u, 0u, 0u};
}

__global__ void k_pack(const float* __restrict__ W_ih, const float* __restrict__ W_hh,
                       const float* __restrict__ b_ih, const float* __restrict__ b_hh,
                       unsigned char* ws) {
  unsigned short* whh = (unsigned short*)(ws + OFF_WHH);
  unsigned short* wih = (unsigned short*)(ws + OFF_WIH);
  float* bias = (float*)(ws + OFF_BIAS);
  int tid = blockIdx.x * blockDim.x + threadIdx.x;
  int np = gridDim.x * blockDim.x;
  for (int i = tid; i < G4 * HDIM; i += np) whh[i] = f2bf(W_hh[i]);
  for (int i = tid; i < G4 * DIN;  i += np) wih[i] = f2bf(W_ih[i]);
  for (int i = tid; i < G4;        i += np) bias[i] = b_ih[i] + b_hh[i];
}

// stage x[t] chunk c (8 f32 -> 8 bf16) of batch-row m into A_s x-region
__device__ __forceinline__ void stage_x(const float* __restrict__ x, unsigned short* A_s,
                                        int g, int m, int c, int tstep) {
  const float* xb = x + ((size_t)(g * GB + m) * 1024 + tstep) * 256 + c * 8;
  float4 f0 = *(const float4*)(xb);
  float4 f1 = *(const float4*)(xb + 4);
  union { bf16x8 v; unsigned short s[8]; } u;
  u.s[0] = f2bf(f0.x); u.s[1] = f2bf(f0.y); u.s[2] = f2bf(f0.z); u.s[3] = f2bf(f0.w);
  u.s[4] = f2bf(f1.x); u.s[5] = f2bf(f1.y); u.s[6] = f2bf(f1.z); u.s[7] = f2bf(f1.w);
  *(bf16x8*)(A_s + m * 776 + 512 + c * 8) = u.v;
}

// 512 WGs x 512 thr; 32 participants per XCD (group = physical XCD).
// WG: 8 batches x 64 gate cols, K=768, weights in LDS.
// Exchange: TAGGED-DATA ring in XCD-local L2. Word = (bf16(h)<<16)|(step tag).
// Producer: plain store (write-through to L2), no drain, no counters.
// Consumer: plain vector load (L1-safe: slot address cold for 16 steps);
//           per-word tag check; rare stale words re-read via FAILED CAS
//           (RMW-class executes at L2 -> fresh; writes nothing on failure).
__global__ __launch_bounds__(BLOCK, 1) void k_lstm(unsigned char* ws,
                                                   const float* __restrict__ x,
                                                   float* __restrict__ out) {
  __shared__ __attribute__((aligned(16))) unsigned short A_s[16 * 776];   // [16][512h|256x|8pad]
  __shared__ __attribute__((aligned(16))) unsigned short Whh_s[64 * 520]; // [64 cols][512+8]
  __shared__ __attribute__((aligned(16))) unsigned short Wih_s[64 * 264]; // [64 cols][256+8]
  __shared__ __attribute__((aligned(16))) float glp[2 * 16 * 64];         // 2 K-half partials
  __shared__ int s_rank;

  const int tid = threadIdx.x;

  unsigned xcc;
  asm("s_getreg_b32 %0, hwreg(HW_REG_XCC_ID)" : "=s"(xcc));
  xcc &= 7;
  unsigned* xcnt = (unsigned*)(ws + OFF_XCNT);
  if (tid == 0)
    s_rank = (int)__hip_atomic_fetch_add(&xcnt[xcc], 1u, __ATOMIC_RELAXED, __HIP_MEMORY_SCOPE_AGENT);
  __syncthreads();
  const int rank = s_rank;
  if (rank >= GWG) return;                    // non-participant exits, frees CU

  const int g  = (int)xcc;
  const int jt = rank;                        // j-tile 0..31 (16 j each)

  const unsigned short* whh_g = (const unsigned short*)(ws + OFF_WHH);
  const unsigned short* wih_g = (const unsigned short*)(ws + OFF_WIH);
  const float*          bias_g = (const float*)(ws + OFF_BIAS);
  unsigned*             hring = (unsigned*)(ws + OFF_H) + (size_t)g * (NBUF * GB * HDIM);

  const int lane = tid & 63, w = tid >> 6;     // 8 waves
  const int ns   = w & 3;                      // gate tile (i,f,g,o)
  const int whigh = (w < 4);                   // kk 12..23 half (incl. 8 x-kk)
  const int arow = lane & 15;
  const int kg   = (lane >> 4) * 8;
  const int rl   = ns * 16 + (lane & 15);      // W LDS row = gate col within WG

  // --- preload W slices: LDS row rl0 (0..63) = gate col; gate=rl0>>4, jloc=rl0&15 ---
  {
    int rl0 = tid >> 3, part = tid & 7;        // 8 parts: Whh 64 bf16, Wih 32 bf16
    int grow = (rl0 >> 4) * 512 + jt * 16 + (rl0 & 15);
    const unsigned short* src = whh_g + (size_t)grow * 512 + part * 64;
    unsigned short* dst = Whh_s + rl0 * 520 + part * 64;
    #pragma unroll
    for (int i = 0; i < 8; ++i) *(bf16x8*)(dst + i * 8) = *(const bf16x8*)(src + i * 8);
    const unsigned short* src2 = wih_g + (size_t)grow * 256 + part * 32;
    unsigned short* dst2 = Wih_s + rl0 * 264 + part * 32;
    #pragma unroll
    for (int i = 0; i < 4; ++i) *(bf16x8*)(dst2 + i * 8) = *(const bf16x8*)(src2 + i * 8);
  }

  // --- zero A_s (h(0)=0; pad rows stay finite forever) ---
  {
    unsigned* a32 = (unsigned*)A_s;
    for (int i = tid; i < 16 * 776 / 2; i += BLOCK) a32[i] = 0;
  }

  float biasr[4];
  float c_reg = 0.f;
  const int ub = tid >> 4, jl = tid & 15;     // updater mapping (tid<128: waves 0,1)
  if (tid < 128) {
    #pragma unroll
    for (int gt = 0; gt < 4; ++gt)
      biasr[gt] = bias_g[gt * 512 + jt * 16 + jl];
  }

  const int sm = tid >> 6, sc = tid & 63;      // staging: 8 rows x 64 thr

  __syncthreads();

  // --- preamble: stage x(0); accX(0) on high waves; stage x(1) ---
  if (sc < 32) stage_x(x, A_s, g, sm, sc, 0);
  __syncthreads();
  f32x4 accX = {0.f, 0.f, 0.f, 0.f};
  if (whigh) {
    f32x4 xa = {0.f,0.f,0.f,0.f}, xb2 = {0.f,0.f,0.f,0.f};
    #pragma unroll
    for (int xk = 0; xk < 4; ++xk) {
      bf16x8 a = *(const bf16x8*)(A_s + arow * 776 + 512 + xk * 32 + kg);
      bf16x8 b = *(const bf16x8*)(Wih_s + rl * 264 + xk * 32 + kg);
      xa = __builtin_amdgcn_mfma_f32_16x16x32_bf16(a, b, xa, 0, 0, 0);
    }
    #pragma unroll
    for (int xk = 4; xk < 8; ++xk) {
      bf16x8 a = *(const bf16x8*)(A_s + arow * 776 + 512 + xk * 32 + kg);
      bf16x8 b = *(const bf16x8*)(Wih_s + rl * 264 + xk * 32 + kg);
      xb2 = __builtin_amdgcn_mfma_f32_16x16x32_bf16(a, b, xb2, 0, 0, 0);
    }
    #pragma unroll
    for (int r = 0; r < 4; ++r) accX[r] = xa[r] + xb2[r];
  }
  __syncthreads();
  if (sc < 32) stage_x(x, A_s, g, sm, sc, 1);
  __syncthreads();

  // --- main loop. Top of iter t: A_s-h = h(t), A_s-x = x(t+1),
  //     accX (high waves) = x-partial(t). ---
  for (int t = 0; t < T_STEPS; ++t) {
    // phase1: h-part MFMAs for this wave's K-half
    f32x4 accfin;
    if (whigh) {                               // kk 12..15 + carried accX
      f32x4 a0 = accX;
      #pragma unroll
      for (int u = 0; u < 4; ++u) {
        int kk = 12 + u;
        bf16x8 a = *(const bf16x8*)(A_s + arow * 776 + kk * 32 + kg);
        bf16x8 b = *(const bf16x8*)(Whh_s + rl * 520 + kk * 32 + kg);
        a0 = __builtin_amdgcn_mfma_f32_16x16x32_bf16(a, b, a0, 0, 0, 0);
      }
      accfin = a0;
    } else {                                   // kk 0..11, two independent chains
      f32x4 a0 = {0.f,0.f,0.f,0.f}, a1 = {0.f,0.f,0.f,0.f};
      #pragma unroll
      for (int u = 0; u < 6; ++u) {
        bf16x8 a = *(const bf16x8*)(A_s + arow * 776 + u * 32 + kg);
        bf16x8 b = *(const bf16x8*)(Whh_s + rl * 520 + u * 32 + kg);
        a0 = __builtin_amdgcn_mfma_f32_16x16x32_bf16(a, b, a0, 0, 0, 0);
      }
      #pragma unroll
      for (int u = 6; u < 12; ++u) {
        bf16x8 a = *(const bf16x8*)(A_s + arow * 776 + u * 32 + kg);
        bf16x8 b = *(const bf16x8*)(Whh_s + rl * 520 + u * 32 + kg);
        a1 = __builtin_amdgcn_mfma_f32_16x16x32_bf16(a, b, a1, 0, 0, 0);
      }
      #pragma unroll
      for (int r = 0; r < 4; ++r) accfin[r] = a0[r] + a1[r];
    }
    {
      const int half = whigh ? 1 : 0;
      #pragma unroll
      for (int r = 0; r < 4; ++r) {
        int m = (lane >> 4) * 4 + r;           // C/D: row=(lane>>4)*4+reg, col=lane&15
        glp[half * 1024 + m * 64 + ns * 16 + (lane & 15)] = accfin[r];
      }
    }
    __syncthreads();                           // S1: partials visible; A_s-h dead

    // phase2: update (tid<128): gates -> c,h; tagged h store + out store (no drain)
    if (tid < 128) {
      float gs[4];
      #pragma unroll
      for (int gt = 0; gt < 4; ++gt)
        gs[gt] = glp[ub * 64 + gt * 16 + jl]
               + glp[1024 + ub * 64 + gt * 16 + jl] + biasr[gt];
      float cv = sigm(gs[1]) * c_reg + sigm(gs[0]) * tanh_f(gs[2]);
      c_reg = cv;
      float hv = sigm(gs[3]) * tanh_f(cv);
      if (t + 1 < T_STEPS) {
        unsigned* hd = hring + (size_t)((t + 1) & (NBUF - 1)) * (GB * HDIM);
        hd[ub * HDIM + jt * 16 + jl] =
            ((unsigned)f2bf(hv) << 16) | (unsigned)((t + 1) & 0xFFFF);
      }
      out[((size_t)t * 64 + g * GB + ub) * 512 + jt * 16 + jl] = sigm(hv);
    }

    if (t + 1 < T_STEPS) {
      // phase3: x(t+1) partial on high waves (overlaps producers' store flight)
      if (whigh) {
        f32x4 xa = {0.f,0.f,0.f,0.f}, xb2 = {0.f,0.f,0.f,0.f};
        #pragma unroll
        for (int xk = 0; xk < 4; ++xk) {
          bf16x8 a = *(const bf16x8*)(A_s + arow * 776 + 512 + xk * 32 + kg);
          bf16x8 b = *(const bf16x8*)(Wih_s + rl * 264 + xk * 32 + kg);
          xa = __builtin_amdgcn_mfma_f32_16x16x32_bf16(a, b, xa, 0, 0, 0);
        }
        #pragma unroll
        for (int xk = 4; xk < 8; ++xk) {
          bf16x8 a = *(const bf16x8*)(A_s + arow * 776 + 512 + xk * 32 + kg);
          bf16x8 b = *(const bf16x8*)(Wih_s + rl * 264 + xk * 32 + kg);
          xb2 = __builtin_amdgcn_mfma_f32_16x16x32_bf16(a, b, xb2, 0, 0, 0);
        }
        #pragma unroll
        for (int r = 0; r < 4; ++r) accX[r] = xa[r] + xb2[r];
      }
      __syncthreads();                         // S2: A_s x-region reads done

      // phase4: stage h(t+1) from tagged ring (8 u32/thread, contiguous 32B)
      {
        const unsigned tag = (unsigned)((t + 1) & 0xFFFF);
        unsigned* base = hring + (size_t)((t + 1) & (NBUF - 1)) * (GB * HDIM)
                       + sm * HDIM + sc * 8;
        u32x4 v0 = *(const u32x4*)(base);
        u32x4 v1 = *(const u32x4*)(base + 4);
        unsigned vv[8];
        #pragma unroll
        for (int i = 0; i < 4; ++i) { vv[i] = v0[i]; vv[4 + i] = v1[i]; }
        bool ok = true;
        #pragma unroll
        for (int i = 0; i < 8; ++i) ok = ok && ((vv[i] & 0xFFFFu) == tag);
        if (!ok) {
          // rare path: re-read stale words via failed CAS (fresh at L2, writes nothing)
          #pragma unroll
          for (int i = 0; i < 8; ++i) {
            while ((vv[i] & 0xFFFFu) != tag) {
              unsigned expected = 0xFFFFFFFFu;   // impossible word (tag field 0xFFFF)
              __hip_atomic_compare_exchange_strong(base + i, &expected, 0xFFFFFFFFu,
                                                   __ATOMIC_RELAXED, __ATOMIC_RELAXED,
                                                   __HIP_MEMORY_SCOPE_WORKGROUP);
              vv[i] = expected;                  // failed CAS returns current value
            }
          }
        }
        union { bf16x8 b; unsigned short s[8]; } u;
        #pragma unroll
        for (int i = 0; i < 8; ++i) u.s[i] = (unsigned short)(vv[i] >> 16);
        *(bf16x8*)(A_s + sm * 776 + sc * 8) = u.b;
        if (t + 2 < T_STEPS && sc < 32) stage_x(x, A_s, g, sm, sc, t + 2);
      }
      __syncthreads();                         // S3: A_s consistent for next iter
    }
  }
}

extern "C" void kernel_launch(void* const* d_in, const int* in_sizes, int n_in,
                              void* d_out, int out_size, void* d_ws, size_t ws_size,
                              hipStream_t stream) {
  const float* x    = (const float*)d_in[0];
  const float* W_ih = (const float*)d_in[1];
  const float* W_hh = (const float*)d_in[2];
  const float* b_ih = (const float*)d_in[3];
  const float* b_hh = (const float*)d_in[4];
  float* out = (float*)d_out;
  unsigned char* ws = (unsigned char*)d_ws;

  hipLaunchKernelGGL(k_init, dim3(512),  dim3(256), 0, stream, ws);
  hipLaunchKernelGGL(k_pack, dim3(1024), dim3(256), 0, stream, W_ih, W_hh, b_ih, b_hh, ws);
  hipLaunchKernelGGL(k_lstm, dim3(512),  dim3(BLOCK), 0, stream, ws, x, out);
}

// Round 13
// 3254.563 us; speedup vs baseline: 14.1480x; 14.1480x over previous
//
#include <hip/hip_runtime.h>
#include <stdint.h>

#define T_STEPS 1024
#define BATCH   64
#define DIN     256
#define HDIM    512
#define G4      2048
#define NGRP    8        // groups = XCDs
#define GWG     32       // WGs per group
#define GB      8        // batches per group
#define NBUF    16       // h ring depth (guarantees L1 eviction between slot reuses)
#define BLOCK   512

// ---- workspace layout (bytes) ----
// Per-group sync region (8 KB of 128B lines): [0..7]=arrive, [8]=lvl2, [9..40]=GO mailboxes
#define OFF_XCNT  0                            // 8 ints: per-XCD rank counters
#define OFF_SYNC  4096                         // [8 groups][8192 B]
#define OFF_BIAS  (4096 + NGRP*8192)           // 2048 f32 (b_ih + b_hh)
#define OFF_WHH   (OFF_BIAS + 8192)            // 2048*512 bf16 (2 MB)
#define OFF_WIH   (OFF_WHH + G4*HDIM*2)        // 2048*256 bf16 (1 MB)
#define OFF_H     (OFF_WIH + G4*DIN*2)         // [NGRP][NBUF][8][512] bf16 = 1 MB

typedef __attribute__((ext_vector_type(8))) short bf16x8;
typedef __attribute__((ext_vector_type(4))) float f32x4;

__device__ __forceinline__ unsigned short f2bf(float f) {
  union { float f; unsigned u; } v; v.f = f;
  unsigned r = v.u + 0x7FFF + ((v.u >> 16) & 1);
  return (unsigned short)(r >> 16);
}
__device__ __forceinline__ float sigm(float x)   { return 1.0f / (1.0f + __expf(-x)); }
__device__ __forceinline__ float tanh_f(float x) { return 2.0f / (1.0f + __expf(-2.0f * x)) - 1.0f; }

__global__ void k_init(unsigned char* ws) {
  int tid = blockIdx.x * blockDim.x + threadIdx.x;
  unsigned* w32 = (unsigned*)ws;
  for (int i = tid; i < (int)(OFF_BIAS / 4); i += gridDim.x * blockDim.x) w32[i] = 0;
}

__global__ void k_pack(const float* __restrict__ W_ih, const float* __restrict__ W_hh,
                       const float* __restrict__ b_ih, const float* __restrict__ b_hh,
                       unsigned char* ws) {
  unsigned short* whh = (unsigned short*)(ws + OFF_WHH);
  unsigned short* wih = (unsigned short*)(ws + OFF_WIH);
  float* bias = (float*)(ws + OFF_BIAS);
  int tid = blockIdx.x * blockDim.x + threadIdx.x;
  int np = gridDim.x * blockDim.x;
  for (int i = tid; i < G4 * HDIM; i += np) whh[i] = f2bf(W_hh[i]);
  for (int i = tid; i < G4 * DIN;  i += np) wih[i] = f2bf(W_ih[i]);
  for (int i = tid; i < G4;        i += np) bias[i] = b_ih[i] + b_hh[i];
}

// stage x[t] chunk c (8 f32 -> 8 bf16) of batch-row m into A_s x-region
__device__ __forceinline__ void stage_x(const float* __restrict__ x, unsigned short* A_s,
                                        int g, int m, int c, int tstep) {
  const float* xb = x + ((size_t)(g * GB + m) * 1024 + tstep) * 256 + c * 8;
  float4 f0 = *(const float4*)(xb);
  float4 f1 = *(const float4*)(xb + 4);
  union { bf16x8 v; unsigned short s[8]; } u;
  u.s[0] = f2bf(f0.x); u.s[1] = f2bf(f0.y); u.s[2] = f2bf(f0.z); u.s[3] = f2bf(f0.w);
  u.s[4] = f2bf(f1.x); u.s[5] = f2bf(f1.y); u.s[6] = f2bf(f1.z); u.s[7] = f2bf(f1.w);
  *(bf16x8*)(A_s + m * 776 + 512 + c * 8) = u.v;
}

// 512 WGs x 512 thr; 32 participants per XCD (group = physical XCD).
// WG: 8 batches x 64 gate cols, K=768, weights in LDS; 8-wave K-split compute
// (verified r11/r12). Sync topology (all XCD-L2-local, RMW-gated):
//   wave0 = sole updater: h stores -> vmcnt(0) -> ONE fetch_add on line rank&7
//   line leader (4th arrival) -> lvl2 fetch_add; lvl2 completer (8th) = master
//   master: 32 PLAIN stores GO=t+1 to private mailboxes (distinct lines, pipelined)
//   each WG: wave7 RMW-polls its OWN mailbox (no cross-poller contention)
// h data: plain stores/loads on NBUF=16 ring; load is after poll => after
// producer's vmcnt(0) => store landed in L2 (r12 lesson).
__global__ __launch_bounds__(BLOCK, 1) void k_lstm(unsigned char* ws,
                                                   const float* __restrict__ x,
                                                   float* __restrict__ out) {
  __shared__ __attribute__((aligned(16))) unsigned short A_s[16 * 776];   // [16][512h|256x|8pad]
  __shared__ __attribute__((aligned(16))) unsigned short Whh_s[64 * 520]; // [64 cols][512+8]
  __shared__ __attribute__((aligned(16))) unsigned short Wih_s[64 * 264]; // [64 cols][256+8]
  __shared__ __attribute__((aligned(16))) float glp[2 * 16 * 64];         // 2 K-half partials
  __shared__ int s_rank;

  const int tid = threadIdx.x;

  unsigned xcc;
  asm("s_getreg_b32 %0, hwreg(HW_REG_XCC_ID)" : "=s"(xcc));
  xcc &= 7;
  unsigned* xcnt = (unsigned*)(ws + OFF_XCNT);
  if (tid == 0)
    s_rank = (int)__hip_atomic_fetch_add(&xcnt[xcc], 1u, __ATOMIC_RELAXED, __HIP_MEMORY_SCOPE_AGENT);
  __syncthreads();
  const int rank = s_rank;
  if (rank >= GWG) return;                    // non-participant exits, frees CU

  const int g  = (int)xcc;
  const int jt = rank;                        // j-tile 0..31 (16 j each)

  const unsigned short* whh_g = (const unsigned short*)(ws + OFF_WHH);
  const unsigned short* wih_g = (const unsigned short*)(ws + OFF_WIH);
  const float*          bias_g = (const float*)(ws + OFF_BIAS);
  unsigned short*       hring = (unsigned short*)(ws + OFF_H) + (size_t)g * (NBUF * GB * HDIM);
  unsigned*             sync  = (unsigned*)(ws + OFF_SYNC + g * 8192);  // 128B lines, 32 dw apart

  const int lane = tid & 63, w = tid >> 6;     // 8 waves
  const int ns   = w & 3;                      // gate tile (i,f,g,o)
  const int whigh = (w < 4);                   // kk 12..23 half (incl. 8 x-kk)
  const int arow = lane & 15;
  const int kg   = (lane >> 4) * 8;
  const int rl   = ns * 16 + (lane & 15);      // W LDS row = gate col within WG

  // --- preload W slices: LDS row rl0 (0..63) = gate col; gate=rl0>>4, jloc=rl0&15 ---
  {
    int rl0 = tid >> 3, part = tid & 7;        // 8 parts: Whh 64 bf16, Wih 32 bf16
    int grow = (rl0 >> 4) * 512 + jt * 16 + (rl0 & 15);
    const unsigned short* src = whh_g + (size_t)grow * 512 + part * 64;
    unsigned short* dst = Whh_s + rl0 * 520 + part * 64;
    #pragma unroll
    for (int i = 0; i < 8; ++i) *(bf16x8*)(dst + i * 8) = *(const bf16x8*)(src + i * 8);
    const unsigned short* src2 = wih_g + (size_t)grow * 256 + part * 32;
    unsigned short* dst2 = Wih_s + rl0 * 264 + part * 32;
    #pragma unroll
    for (int i = 0; i < 4; ++i) *(bf16x8*)(dst2 + i * 8) = *(const bf16x8*)(src2 + i * 8);
  }

  // --- zero A_s (h(0)=0; pad rows stay finite forever) ---
  {
    unsigned* a32 = (unsigned*)A_s;
    for (int i = tid; i < 16 * 776 / 2; i += BLOCK) a32[i] = 0;
  }

  // --- updater setup: wave0 only; lane -> (ub = lane>>3, jl0 = (lane&7)*2, 2 j's) ---
  float biasr[2][4];
  float c_reg[2] = {0.f, 0.f};
  const int ub  = lane >> 3;
  const int jl0 = (lane & 7) * 2;
  if (w == 0) {
    #pragma unroll
    for (int e = 0; e < 2; ++e)
      #pragma unroll
      for (int gt = 0; gt < 4; ++gt)
        biasr[e][gt] = bias_g[gt * 512 + jt * 16 + jl0 + e];
  }

  const int sm = tid >> 6, sc = tid & 63;      // staging: 8 rows x 64 thr

  __syncthreads();

  // --- preamble: stage x(0); accX(0) on high waves; stage x(1) ---
  if (sc < 32) stage_x(x, A_s, g, sm, sc, 0);
  __syncthreads();
  f32x4 accX = {0.f, 0.f, 0.f, 0.f};
  if (whigh) {
    f32x4 xa = {0.f,0.f,0.f,0.f}, xb2 = {0.f,0.f,0.f,0.f};
    #pragma unroll
    for (int xk = 0; xk < 4; ++xk) {
      bf16x8 a = *(const bf16x8*)(A_s + arow * 776 + 512 + xk * 32 + kg);
      bf16x8 b = *(const bf16x8*)(Wih_s + rl * 264 + xk * 32 + kg);
      xa = __builtin_amdgcn_mfma_f32_16x16x32_bf16(a, b, xa, 0, 0, 0);
    }
    #pragma unroll
    for (int xk = 4; xk < 8; ++xk) {
      bf16x8 a = *(const bf16x8*)(A_s + arow * 776 + 512 + xk * 32 + kg);
      bf16x8 b = *(const bf16x8*)(Wih_s + rl * 264 + xk * 32 + kg);
      xb2 = __builtin_amdgcn_mfma_f32_16x16x32_bf16(a, b, xb2, 0, 0, 0);
    }
    #pragma unroll
    for (int r = 0; r < 4; ++r) accX[r] = xa[r] + xb2[r];
  }
  __syncthreads();
  if (sc < 32) stage_x(x, A_s, g, sm, sc, 1);
  __syncthreads();

  // --- main loop. Top of iter t: A_s-h = h(t), A_s-x = x(t+1),
  //     accX (high waves) = x-partial(t). ---
  for (int t = 0; t < T_STEPS; ++t) {
    // phase1: h-part MFMAs for this wave's K-half
    f32x4 accfin;
    if (whigh) {                               // kk 12..15 + carried accX
      f32x4 a0 = accX;
      #pragma unroll
      for (int u = 0; u < 4; ++u) {
        int kk = 12 + u;
        bf16x8 a = *(const bf16x8*)(A_s + arow * 776 + kk * 32 + kg);
        bf16x8 b = *(const bf16x8*)(Whh_s + rl * 520 + kk * 32 + kg);
        a0 = __builtin_amdgcn_mfma_f32_16x16x32_bf16(a, b, a0, 0, 0, 0);
      }
      accfin = a0;
    } else {                                   // kk 0..11, two independent chains
      f32x4 a0 = {0.f,0.f,0.f,0.f}, a1 = {0.f,0.f,0.f,0.f};
      #pragma unroll
      for (int u = 0; u < 6; ++u) {
        bf16x8 a = *(const bf16x8*)(A_s + arow * 776 + u * 32 + kg);
        bf16x8 b = *(const bf16x8*)(Whh_s + rl * 520 + u * 32 + kg);
        a0 = __builtin_amdgcn_mfma_f32_16x16x32_bf16(a, b, a0, 0, 0, 0);
      }
      #pragma unroll
      for (int u = 6; u < 12; ++u) {
        bf16x8 a = *(const bf16x8*)(A_s + arow * 776 + u * 32 + kg);
        bf16x8 b = *(const bf16x8*)(Whh_s + rl * 520 + u * 32 + kg);
        a1 = __builtin_amdgcn_mfma_f32_16x16x32_bf16(a, b, a1, 0, 0, 0);
      }
      #pragma unroll
      for (int r = 0; r < 4; ++r) accfin[r] = a0[r] + a1[r];
    }
    {
      const int half = whigh ? 1 : 0;
      #pragma unroll
      for (int r = 0; r < 4; ++r) {
        int m = (lane >> 4) * 4 + r;           // C/D: row=(lane>>4)*4+reg, col=lane&15
        glp[half * 1024 + m * 64 + ns * 16 + (lane & 15)] = accfin[r];
      }
    }
    __syncthreads();                           // S1: partials visible

    // phase2 (wave0 only): update 2 j's; packed u32 h store; vmcnt(0); arrive+tree
    float hv[2];
    if (w == 0) {
      #pragma unroll
      for (int e = 0; e < 2; ++e) {
        int jl = jl0 + e;
        float gi = glp[ub * 64 +      jl] + glp[1024 + ub * 64 +      jl] + biasr[e][0];
        float gf = glp[ub * 64 + 16 + jl] + glp[1024 + ub * 64 + 16 + jl] + biasr[e][1];
        float gg = glp[ub * 64 + 32 + jl] + glp[1024 + ub * 64 + 32 + jl] + biasr[e][2];
        float go = glp[ub * 64 + 48 + jl] + glp[1024 + ub * 64 + 48 + jl] + biasr[e][3];
        float cv = sigm(gf) * c_reg[e] + sigm(gi) * tanh_f(gg);
        c_reg[e] = cv;
        hv[e] = sigm(go) * tanh_f(cv);
      }
      if (t + 1 < T_STEPS) {
        unsigned* hd32 = (unsigned*)(hring + (size_t)((t + 1) & (NBUF - 1)) * (GB * HDIM));
        hd32[ub * 256 + jt * 8 + (jl0 >> 1)] =
            (unsigned)f2bf(hv[0]) | ((unsigned)f2bf(hv[1]) << 16);
        asm volatile("s_waitcnt vmcnt(0)" ::: "memory");   // wave0's h stores at L2
        if (lane == 0) {
          unsigned v = __hip_atomic_fetch_add(&sync[(rank & 7) * 32], 1u,
                                              __ATOMIC_RELAXED, __HIP_MEMORY_SCOPE_WORKGROUP);
          if (v == 4u * (unsigned)(t + 1) - 1u) {           // line leader (4 WGs/line)
            unsigned w2 = __hip_atomic_fetch_add(&sync[8 * 32], 1u,
                                                 __ATOMIC_RELAXED, __HIP_MEMORY_SCOPE_WORKGROUP);
            if (w2 == 8u * (unsigned)(t + 1) - 1u) {        // master: plain-store GO
              #pragma unroll
              for (int r = 0; r < GWG; ++r)
                sync[(9 + r) * 32] = (unsigned)(t + 1);
            }
          }
        }
      }
      // out after arrive: HBM ack never gates the group
      *(float2*)(out + ((size_t)t * 64 + g * GB + ub) * 512 + jt * 16 + jl0) =
          make_float2(sigm(hv[0]), sigm(hv[1]));
    }

    if (t + 1 < T_STEPS) {
      // phase3: x(t+1) partial on high waves (overlaps sync tree)
      if (whigh) {
        f32x4 xa = {0.f,0.f,0.f,0.f}, xb2 = {0.f,0.f,0.f,0.f};
        #pragma unroll
        for (int xk = 0; xk < 4; ++xk) {
          bf16x8 a = *(const bf16x8*)(A_s + arow * 776 + 512 + xk * 32 + kg);
          bf16x8 b = *(const bf16x8*)(Wih_s + rl * 264 + xk * 32 + kg);
          xa = __builtin_amdgcn_mfma_f32_16x16x32_bf16(a, b, xa, 0, 0, 0);
        }
        #pragma unroll
        for (int xk = 4; xk < 8; ++xk) {
          bf16x8 a = *(const bf16x8*)(A_s + arow * 776 + 512 + xk * 32 + kg);
          bf16x8 b = *(const bf16x8*)(Wih_s + rl * 264 + xk * 32 + kg);
          xb2 = __builtin_amdgcn_mfma_f32_16x16x32_bf16(a, b, xb2, 0, 0, 0);
        }
        #pragma unroll
        for (int r = 0; r < 4; ++r) accX[r] = xa[r] + xb2[r];
      }
      // phase4: private-mailbox poll (wave7 lane0); RMW = L2-fresh; live by induction
      if (tid == 448) {
        const unsigned target = (unsigned)(t + 1);
        for (;;) {
          unsigned v = __hip_atomic_fetch_or(&sync[(9 + rank) * 32], 0x80000000u,
                                             __ATOMIC_RELAXED, __HIP_MEMORY_SCOPE_WORKGROUP);
          if ((v & 0x7FFFFFFFu) >= target) break;
        }
      }
      __syncthreads();                         // S2: h(t+1) ready group-wide; x reads done

      // phase5: stage h(t+1) from ring (plain loads: after poll => stores landed;
      // slot address cold for 16 steps => L1-safe) + x(t+2)
      {
        const unsigned short* hs = hring + (size_t)((t + 1) & (NBUF - 1)) * (GB * HDIM)
                                 + sm * HDIM + sc * 8;
        bf16x8 h0 = *(const bf16x8*)(hs);
        *(bf16x8*)(A_s + sm * 776 + sc * 8) = h0;
        if (t + 2 < T_STEPS && sc < 32) stage_x(x, A_s, g, sm, sc, t + 2);
      }
      __syncthreads();                         // S3: A_s consistent for next iter
    }
  }
}

extern "C" void kernel_launch(void* const* d_in, const int* in_sizes, int n_in,
                              void* d_out, int out_size, void* d_ws, size_t ws_size,
                              hipStream_t stream) {
  const float* x    = (const float*)d_in[0];
  const float* W_ih = (const float*)d_in[1];
  const float* W_hh = (const float*)d_in[2];
  const float* b_ih = (const float*)d_in[3];
  const float* b_hh = (const float*)d_in[4];
  float* out = (float*)d_out;
  unsigned char* ws = (unsigned char*)d_ws;

  hipLaunchKernelGGL(k_init, dim3(32),   dim3(256), 0, stream, ws);
  hipLaunchKernelGGL(k_pack, dim3(1024), dim3(256), 0, stream, W_ih, W_hh, b_ih, b_hh, ws);
  hipLaunchKernelGGL(k_lstm, dim3(512),  dim3(BLOCK), 0, stream, ws, x, out);
}